// Round 12
// baseline (6261.462 us; speedup 1.0000x reference)
//
#include <hip/hip_runtime.h>
#include <math.h>

#define TT 1024
#define U1 128
#define U2 32
#define NCOL 480   // 384 rk1 gate-cols + 96 k2 cols (all dot against h1)
#define NUQ 4      // u-quarters

typedef float f2 __attribute__((ext_vector_type(2)));

// v_pk_fma_f32 with SGPR-pair h source (VOP3P allows 1 scalar operand).
// PKS_LO: both halves multiply by hs.x ; PKS_HI: both halves multiply by hs.y
// (op_sel pattern identical to the R7/R10 bit-exact-verified VGPR version)
#define PKS_LO(acc, w, hs) asm("v_pk_fma_f32 %0, %1, %2, %0 op_sel:[0,0,0] op_sel_hi:[1,0,1]" \
                               : "+v"(acc) : "v"(w), "s"(hs))
#define PKS_HI(acc, w, hs) asm("v_pk_fma_f32 %0, %1, %2, %0 op_sel:[0,1,0] op_sel_hi:[1,1,1]" \
                               : "+v"(acc) : "v"(w), "s"(hs))

__device__ __forceinline__ float fast_tanh(float v) {
    float e = __expf(2.f * v);      // v>>0: e=inf -> 1; v<<0: e=0 -> -1 (NaN-free)
    return 1.f - 2.f / (e + 1.f);
}
__device__ __forceinline__ float fast_sig(float v) {
    return 1.f / (1.f + __expf(-v));
}
__device__ __forceinline__ float rlf(float v, int l) {
    return __int_as_float(__builtin_amdgcn_readlane(__float_as_int(v), l));
}

// SGPR-BROADCAST DOT. 256 blocks x 512 threads; block owns batches {2b,2b+1};
// 1 block/CU (co-residency refuted in R11). h is wave-uniform -> fetch once
// per wave (1 ds_read_b32/batch), readlane into SGPRs, feed pk_fma's scalar
// operand. DS: 18 -> 4 inst/wave/step; VALU: 64 rl + 128 pk per thread.
// Mapping (wave-uniform uq so readlane indices are correct):
//   wave w: uq = w&3, ub = 32*uq; quad q = (w>>2)*64 + lane (valid q<120),
//   cols c0=4q of [rk1|k2] vs h1. Waves 0&4 cover uq0, 1&5 uq1, etc.
//   waves 4-7 lanes 56-63 (32 thr): rk2 gate-dots for unit r (in-register
//   results, both batches, h2 via b128 from LDS) + GRU2 update (lag as R0).
// GRU1 update: t<256 (waves 0-3, dual role). 2 barriers/step.
// Per-column accumulation stays u-ascending -> bit-identical to R0/R7.
__global__ __launch_bounds__(512, 1)
void gru_stack_kernel(const float* __restrict__ x,   // [512,1024,1]
                      const float* __restrict__ k1,  // [1,384]
                      const float* __restrict__ rk1, // [128,384]
                      const float* __restrict__ b1,  // [2,384]
                      const float* __restrict__ k2,  // [128,96]
                      const float* __restrict__ rk2, // [32,96]
                      const float* __restrict__ b2,  // [2,96]
                      const float* __restrict__ wd,  // [32,1]
                      const float* __restrict__ bd,  // [1]
                      float* __restrict__ out)       // [512,1]
{
    __shared__ __align__(16) float h1s[2][U1];
    __shared__ __align__(16) float h2s[2][U2];
    __shared__ __align__(16) float part1[2][NUQ][NCOL];  // [b][uq][col]
    __shared__ __align__(16) float xs[2][TT];            // staged x rows

    const int t    = threadIdx.x;
    const int b0   = blockIdx.x * 2;
    const int w    = t >> 6, lane = t & 63;
    const int uq   = w & 3, ub = 32 * uq;
    const int q    = ((w >> 2) << 6) + lane;   // quad index within uq
    const bool is_long = (q < 120);            // waves 0-3 all; waves 4-7 lane<56
    const int c0   = 4 * q;
    const bool isRk2 = (w >= 4) && (lane >= 56);
    const int r    = (w - 4) * 8 + (lane - 56);  // GRU2 unit 0..31 (when isRk2)

    if (t < 256) ((float*)h1s)[t] = 0.f;
    if (t < 64)  ((float*)h2s)[t] = 0.f;
    for (int idx = t; idx < 2 * TT; idx += 512)          // coalesced x stage
        ((float*)xs)[idx] = x[b0 * TT + idx];

    // ---------------- long-col weights: 4 cols x 32 u ----------------
    f2 wA[32], wB[32];                  // cols {c0,c0+1} / {c0+2,c0+3}
    if (is_long) {
#pragma unroll
        for (int j = 0; j < 32; ++j) {
            const int u = ub + j;
            float vv[4];
#pragma unroll
            for (int e = 0; e < 4; ++e) {
                const int c = c0 + e;
                vv[e] = (c < 384) ? rk1[u * 384 + c] : k2[u * 96 + (c - 384)];
            }
            wA[j].x = vv[0]; wA[j].y = vv[1];
            wB[j].x = vv[2]; wB[j].y = vv[3];
        }
    }
    // ---------------- rk2 weights + GRU2 state (32 threads) ----------------
    float wz[32], wr_[32], wh[32];
    float bz2 = 0, br2 = 0, bh2x = 0, bh2r = 0, h2A = 0.f, h2B = 0.f;
    if (isRk2) {
#pragma unroll
        for (int u = 0; u < 32; ++u) {
            wz[u]  = rk2[u * 96 + r];
            wr_[u] = rk2[u * 96 + 32 + r];
            wh[u]  = rk2[u * 96 + 64 + r];
        }
        bz2  = b2[r]      + b2[96 + r];
        br2  = b2[32 + r] + b2[96 + 32 + r];
        bh2x = b2[64 + r];
        bh2r = b2[96 + 64 + r];
    }
    // ---------------- GRU1 update setup (t<256, dual role) ----------------
    const int ju = t & 127, bu = t >> 7;
    float k1z = 0, k1r = 0, k1h = 0, bz = 0, br = 0, bhx = 0, bhr = 0, h_old = 0;
    if (t < 256) {
        k1z = k1[ju]; k1r = k1[128 + ju]; k1h = k1[256 + ju];
        bz  = b1[ju]       + b1[384 + ju];
        br  = b1[128 + ju] + b1[384 + 128 + ju];
        bhx = b1[256 + ju];
        bhr = b1[384 + 256 + ju];
    }

    __syncthreads();  // B0: init + x stage visible

    for (int i = 0; i <= TT; ++i) {
        float izA = 0, irA = 0, ihA = 0, izB = 0, irB = 0, ihB = 0;  // rk2 results
        if (is_long) {
            // h fetch: ONE b32 per batch (lanes 0-31 hold h[ub..ub+31])
            const float hv0 = h1s[0][ub + (lane & 31)];
            const float hv1 = h1s[1][ub + (lane & 31)];
            f2 aA0 = {0.f, 0.f}, aB0 = {0.f, 0.f};
            f2 aA1 = {0.f, 0.f}, aB1 = {0.f, 0.f};
#pragma unroll
            for (int jj = 0; jj < 16; ++jj) {
                const f2 hs0 = { rlf(hv0, 2 * jj), rlf(hv0, 2 * jj + 1) };
                const f2 hs1 = { rlf(hv1, 2 * jj), rlf(hv1, 2 * jj + 1) };
                PKS_LO(aA0, wA[2 * jj],     hs0);   // u = 2jj
                PKS_HI(aA0, wA[2 * jj + 1], hs0);   // u = 2jj+1
                PKS_LO(aB0, wB[2 * jj],     hs0);
                PKS_HI(aB0, wB[2 * jj + 1], hs0);
                PKS_LO(aA1, wA[2 * jj],     hs1);
                PKS_HI(aA1, wA[2 * jj + 1], hs1);
                PKS_LO(aB1, wB[2 * jj],     hs1);
                PKS_HI(aB1, wB[2 * jj + 1], hs1);
            }
            *(float4*)&part1[0][uq][c0] = make_float4(aA0.x, aA0.y, aB0.x, aB0.y);
            *(float4*)&part1[1][uq][c0] = make_float4(aA1.x, aA1.y, aB1.x, aB1.y);
        } else if (isRk2) {
            // rk2 gate-dots for unit r, both batches; h2 via b128 (only 8
            // lanes/wave -> 1 masked DS inst each)
            const float4* pA = (const float4*)&h2s[0][0];
            const float4* pB = (const float4*)&h2s[1][0];
#pragma unroll
            for (int k = 0; k < 8; ++k) {
                const float4 hA = pA[k], hB = pB[k];
                const float ha[4] = {hA.x, hA.y, hA.z, hA.w};
                const float hb[4] = {hB.x, hB.y, hB.z, hB.w};
#pragma unroll
                for (int e = 0; e < 4; ++e) {
                    const int u = 4 * k + e;
                    izA = fmaf(ha[e], wz[u],  izA);
                    irA = fmaf(ha[e], wr_[u], irA);
                    ihA = fmaf(ha[e], wh[u],  ihA);
                    izB = fmaf(hb[e], wz[u],  izB);
                    irB = fmaf(hb[e], wr_[u], irB);
                    ihB = fmaf(hb[e], wh[u],  ihB);
                }
            }
        }
        __syncthreads();  // B1: partials visible

        if (t < 256 && i < TT) {
            // GRU1 unit update: z/r = relu, hh = tanh (reset_after)
            const float xv = xs[bu][i];
            float iz = part1[bu][0][ju] + part1[bu][1][ju]
                     + part1[bu][2][ju] + part1[bu][3][ju];
            float ir = part1[bu][0][128 + ju] + part1[bu][1][128 + ju]
                     + part1[bu][2][128 + ju] + part1[bu][3][128 + ju];
            float ih = part1[bu][0][256 + ju] + part1[bu][1][256 + ju]
                     + part1[bu][2][256 + ju] + part1[bu][3][256 + ju];
            float z  = fmaxf(fmaf(xv, k1z, bz) + iz, 0.f);
            float rr = fmaxf(fmaf(xv, k1r, br) + ir, 0.f);
            float hh = fast_tanh(fmaf(xv, k1h, bhx) + rr * (ih + bhr));
            h_old = fmaf(z, h_old - hh, hh);
            h1s[bu][ju] = h_old;
        } else if (isRk2 && i >= 1) {
            // GRU2 unit update, both batches (one step behind): sig/sig/relu
            {
                const float xz = part1[0][0][384 + r] + part1[0][1][384 + r]
                               + part1[0][2][384 + r] + part1[0][3][384 + r];
                const float xr = part1[0][0][416 + r] + part1[0][1][416 + r]
                               + part1[0][2][416 + r] + part1[0][3][416 + r];
                const float xh = part1[0][0][448 + r] + part1[0][1][448 + r]
                               + part1[0][2][448 + r] + part1[0][3][448 + r];
                float z  = fast_sig(xz + izA + bz2);
                float rr = fast_sig(xr + irA + br2);
                float hh = fmaxf(xh + bh2x + rr * (ihA + bh2r), 0.f);
                h2A = fmaf(z, h2A - hh, hh);
                h2s[0][r] = h2A;
            }
            {
                const float xz = part1[1][0][384 + r] + part1[1][1][384 + r]
                               + part1[1][2][384 + r] + part1[1][3][384 + r];
                const float xr = part1[1][0][416 + r] + part1[1][1][416 + r]
                               + part1[1][2][416 + r] + part1[1][3][416 + r];
                const float xh = part1[1][0][448 + r] + part1[1][1][448 + r]
                               + part1[1][2][448 + r] + part1[1][3][448 + r];
                float z  = fast_sig(xz + izB + bz2);
                float rr = fast_sig(xr + irB + br2);
                float hh = fmaxf(xh + bh2x + rr * (ihB + bh2r), 0.f);
                h2B = fmaf(z, h2B - hh, hh);
                h2s[1][r] = h2B;
            }
        }
        __syncthreads();  // B2: h updated
    }

    // ---------------- dense head ----------------
    if (t < 64) {
        const int b = t >> 5, j = t & 31;
        float p = h2s[b][j] * wd[j];
#pragma unroll
        for (int m = 16; m >= 1; m >>= 1) p += __shfl_xor(p, m, 64);
        if (j == 0) out[b0 + b] = p + bd[0];
    }
}

extern "C" void kernel_launch(void* const* d_in, const int* in_sizes, int n_in,
                              void* d_out, int out_size, void* d_ws, size_t ws_size,
                              hipStream_t stream) {
    const float* x   = (const float*)d_in[0];
    const float* k1  = (const float*)d_in[1];
    const float* rk1 = (const float*)d_in[2];
    const float* b1  = (const float*)d_in[3];
    const float* k2  = (const float*)d_in[4];
    const float* rk2 = (const float*)d_in[5];
    const float* b2  = (const float*)d_in[6];
    const float* wd  = (const float*)d_in[7];
    const float* bd  = (const float*)d_in[8];
    float* out = (float*)d_out;

    dim3 grid(256), block(512);
    hipLaunchKernelGGL(gru_stack_kernel, grid, block, 0, stream,
                       x, k1, rk1, b1, k2, rk2, b2, wd, bd, out);
}

// Round 13
// 2399.556 us; speedup vs baseline: 2.6094x; 2.6094x over previous
//
#include <hip/hip_runtime.h>
#include <math.h>

#define TT 1024
#define U1 128
#define U2 32
#define PCOL 512   // padded col dim (480 real: 384 rk1 + 96 k2)

typedef float f2 __attribute__((ext_vector_type(2)));

// v_pk_fma_f32 with SGPR-pair scalar source (1 SGPR read/instr: legal).
// Correctness of these macros proven in R12 (absmax 1.490116e-08).
#define PKS_LO(acc, w, hs) asm("v_pk_fma_f32 %0, %1, %2, %0 op_sel:[0,0,0] op_sel_hi:[1,0,1]" \
                               : "+v"(acc) : "v"(w), "s"(hs))
#define PKS_HI(acc, w, hs) asm("v_pk_fma_f32 %0, %1, %2, %0 op_sel:[0,1,0] op_sel_hi:[1,1,1]" \
                               : "+v"(acc) : "v"(w), "s"(hs))

__device__ __forceinline__ float fast_tanh(float v) {
    float e = __expf(2.f * v);      // NaN-free saturation
    return 1.f - 2.f / (e + 1.f);
}
__device__ __forceinline__ float fast_sig(float v) {
    return 1.f / (1.f + __expf(-v));
}
__device__ __forceinline__ float rlf(float v, int l) {
    return __int_as_float(__builtin_amdgcn_readlane(__float_as_int(v), l));
}

// READLANE DOT in the proven 64-float register regime (R10 frame).
// 256 blocks x 1024 threads; block owns batches {2b,2b+1}; 1 block/CU.
// Wave w: uq=w>>2 (wave-uniform u-quarter), pair pi=(w&3)*64+lane (0..255);
//   pi<240: cols {2pi,2pi+1} of [rk1|k2] vs h1[ub..ub+31].
//   h fetch: ONE ds_read_b32/wave (lanes 0-31 batch0, 32-63 batch1), then
//   readlane -> SGPR pairs feed pk_fma scalar operand. Dot DS: ~256 -> ~20.
// Spare lanes (heavy waves w&3==3, lane>=48; sp=uq*16+lane-48): sp<48 own
//   rk2 col-pair {2sp,2sp+1} vs h2 (weights OVERLAY w2 - no extra VGPRs;
//   own h2 readlane block). Their garbage main-dot lands in part1 pad cols.
// GRU1 update: waves 0,1 (batch0) + 4,5 (batch1). GRU2: wave 8. 2 barriers.
// Per-col accumulation u-ascending -> bit-identical to R0 (absmax check).
__global__ __launch_bounds__(1024)
void gru_stack_kernel(const float* __restrict__ x,   // [512,1024,1]
                      const float* __restrict__ k1,  // [1,384]
                      const float* __restrict__ rk1, // [128,384]
                      const float* __restrict__ b1,  // [2,384]
                      const float* __restrict__ k2,  // [128,96]
                      const float* __restrict__ rk2, // [32,96]
                      const float* __restrict__ b2,  // [2,96]
                      const float* __restrict__ wd,  // [32,1]
                      const float* __restrict__ bd,  // [1]
                      float* __restrict__ out)       // [512,1]
{
    __shared__ __align__(16) float h1s[2][U1];
    __shared__ __align__(16) float h2s[2][U2];
    __shared__ __align__(16) float part1[2][4][PCOL]; // [b][uq][col]
    __shared__ __align__(16) float part2[2][96];      // rk2 full sums
    __shared__ __align__(16) float xs[2][TT];         // staged x rows

    const int t    = threadIdx.x;
    const int b0   = blockIdx.x * 2;
    const int w    = t >> 6, lane = t & 63;
    const int uq   = w >> 2, ub = 32 * uq;
    const int pi   = ((w & 3) << 6) + lane;          // 0..255
    const bool heavy = ((w & 3) == 3);
    const int sp   = uq * 16 + (lane - 48);          // valid when heavy&&lane>=48
    const bool isRk2 = heavy && (lane >= 48) && (sp < 48);
    const int c0   = 2 * pi;                         // main col base (pad-safe)
    const int c0r  = 2 * sp;                         // rk2 col base

    if (t < 256) ((float*)h1s)[t] = 0.f;
    if (t < 64)  ((float*)h2s)[t] = 0.f;
    for (int idx = t; idx < 2 * TT; idx += 1024)     // coalesced x stage
        ((float*)xs)[idx] = x[b0 * TT + idx];

    // ---------------- weights: 64 floats/thread (honest VGPR fit) ----------
    f2 w2[32];
    if (pi < 240) {
#pragma unroll
        for (int j = 0; j < 32; ++j) {
            const int u = ub + j;
            const int c1 = c0 + 1;
            const float v0 = (c0 < 384) ? rk1[u * 384 + c0] : k2[u * 96 + (c0 - 384)];
            const float v1 = (c1 < 384) ? rk1[u * 384 + c1] : k2[u * 96 + (c1 - 384)];
            w2[j].x = v0; w2[j].y = v1;
        }
    } else if (isRk2) {
#pragma unroll
        for (int j = 0; j < 32; ++j) {
            w2[j].x = rk2[j * 96 + c0r];
            w2[j].y = rk2[j * 96 + c0r + 1];
        }
    } else {
#pragma unroll
        for (int j = 0; j < 32; ++j) { w2[j].x = 0.f; w2[j].y = 0.f; }
    }

    // ---------------- update roles ----------------
    // GRU1: waves 0,1 (batch0, ju=t) and 4,5 (batch1, ju=t-256)
    const bool isU1 = (w < 2) || (w == 4) || (w == 5);
    const int bu = (w >= 4) ? 1 : 0;
    const int ju = (w < 2) ? t : (t - 256);
    float k1z = 0, k1r = 0, k1h = 0, bz = 0, br = 0, bhx = 0, bhr = 0, h_old = 0;
    if (isU1) {
        k1z = k1[ju]; k1r = k1[128 + ju]; k1h = k1[256 + ju];
        bz  = b1[ju]       + b1[384 + ju];
        br  = b1[128 + ju] + b1[384 + 128 + ju];
        bhx = b1[256 + ju];
        bhr = b1[384 + 256 + ju];
    }
    // GRU2: wave 8 (t 512..575): j2 = tau&31, bb2 = tau>>5
    const bool isU2 = (w == 8);
    const int tau = t - 512, j2 = tau & 31, bb2 = (tau >> 5) & 1;
    float bz2 = 0, br2 = 0, bh2x = 0, bh2r = 0, h2_old = 0;
    if (isU2) {
        bz2  = b2[j2]      + b2[96 + j2];
        br2  = b2[32 + j2] + b2[96 + 32 + j2];
        bh2x = b2[64 + j2];
        bh2r = b2[96 + 64 + j2];
    }

    __syncthreads();  // B0: init + x stage visible

    for (int i = 0; i <= TT; ++i) {
        // ---- phase 1: dots. h via 1 ds_read_b32/wave + readlane->SGPR ----
        // lanes 0-31 carry h1[b=0][ub+lane], lanes 32-63 carry h1[b=1][...]
        const float hv = ((const float*)h1s)[((lane >> 5) << 7) + ub + (lane & 31)];
        f2 a0 = {0.f, 0.f}, a1 = {0.f, 0.f};
#pragma unroll
        for (int jj = 0; jj < 16; ++jj) {
            const f2 hs0 = { rlf(hv, 2 * jj),      rlf(hv, 2 * jj + 1) };
            const f2 hs1 = { rlf(hv, 32 + 2 * jj), rlf(hv, 32 + 2 * jj + 1) };
            PKS_LO(a0, w2[2 * jj],     hs0);     // u = 2jj   (u-ascending)
            PKS_HI(a0, w2[2 * jj + 1], hs0);     // u = 2jj+1
            PKS_LO(a1, w2[2 * jj],     hs1);
            PKS_HI(a1, w2[2 * jj + 1], hs1);
        }
        // spare lanes write garbage to pad cols (c0 in 480..510 < PCOL)
        *(float2*)&part1[0][uq][c0] = make_float2(a0.x, a0.y);
        *(float2*)&part1[1][uq][c0] = make_float2(a1.x, a1.y);

        if (heavy) {                             // wave-uniform branch
            // h2 fetch: lanes 0-31 batch0, 32-63 batch1 (all lanes execute)
            const float hv2 = ((const float*)h2s)[((lane >> 5) << 5) + (lane & 31)];
            f2 r0 = {0.f, 0.f}, r1 = {0.f, 0.f};
#pragma unroll
            for (int jj = 0; jj < 16; ++jj) {
                const f2 gs0 = { rlf(hv2, 2 * jj),      rlf(hv2, 2 * jj + 1) };
                const f2 gs1 = { rlf(hv2, 32 + 2 * jj), rlf(hv2, 32 + 2 * jj + 1) };
                PKS_LO(r0, w2[2 * jj],     gs0);
                PKS_HI(r0, w2[2 * jj + 1], gs0);
                PKS_LO(r1, w2[2 * jj],     gs1);
                PKS_HI(r1, w2[2 * jj + 1], gs1);
            }
            if ((lane >= 48) && (sp < 48)) {     // rk2 lanes only
                *(float2*)&part2[0][c0r] = make_float2(r0.x, r0.y);
                *(float2*)&part2[1][c0r] = make_float2(r1.x, r1.y);
            }
        }
        __syncthreads();  // B1: partials visible

        // ---- phase 2: unit updates ----
        if (isU1 && i < TT) {
            // GRU1: z/r = relu, hh = tanh (reset_after)
            const float xv = xs[bu][i];
            float iz = part1[bu][0][ju] + part1[bu][1][ju]
                     + part1[bu][2][ju] + part1[bu][3][ju];
            float ir = part1[bu][0][128 + ju] + part1[bu][1][128 + ju]
                     + part1[bu][2][128 + ju] + part1[bu][3][128 + ju];
            float ih = part1[bu][0][256 + ju] + part1[bu][1][256 + ju]
                     + part1[bu][2][256 + ju] + part1[bu][3][256 + ju];
            float z  = fmaxf(fmaf(xv, k1z, bz) + iz, 0.f);
            float r  = fmaxf(fmaf(xv, k1r, br) + ir, 0.f);
            float hh = fast_tanh(fmaf(xv, k1h, bhx) + r * (ih + bhr));
            h_old = fmaf(z, h_old - hh, hh);
            h1s[bu][ju] = h_old;
        } else if (isU2 && i >= 1) {
            // GRU2 (one step behind): z/r = sigmoid, hh = relu
            float xz = part1[bb2][0][384 + j2] + part1[bb2][1][384 + j2]
                     + part1[bb2][2][384 + j2] + part1[bb2][3][384 + j2];
            float xr = part1[bb2][0][416 + j2] + part1[bb2][1][416 + j2]
                     + part1[bb2][2][416 + j2] + part1[bb2][3][416 + j2];
            float xh = part1[bb2][0][448 + j2] + part1[bb2][1][448 + j2]
                     + part1[bb2][2][448 + j2] + part1[bb2][3][448 + j2];
            float iz = part2[bb2][j2];
            float ir = part2[bb2][32 + j2];
            float ih = part2[bb2][64 + j2];
            float z  = fast_sig(xz + iz + bz2);
            float r  = fast_sig(xr + ir + br2);
            float hh = fmaxf(xh + bh2x + r * (ih + bh2r), 0.f);
            h2_old = fmaf(z, h2_old - hh, hh);
            h2s[bb2][j2] = h2_old;
        }
        __syncthreads();  // B2: h updated
    }

    // ---------------- dense head ----------------
    if (t < 64) {
        const int b = t >> 5, j = t & 31;
        float p = h2s[b][j] * wd[j];
#pragma unroll
        for (int m = 16; m >= 1; m >>= 1) p += __shfl_xor(p, m, 64);
        if (j == 0) out[b0 + b] = p + bd[0];
    }
}

extern "C" void kernel_launch(void* const* d_in, const int* in_sizes, int n_in,
                              void* d_out, int out_size, void* d_ws, size_t ws_size,
                              hipStream_t stream) {
    const float* x   = (const float*)d_in[0];
    const float* k1  = (const float*)d_in[1];
    const float* rk1 = (const float*)d_in[2];
    const float* b1  = (const float*)d_in[3];
    const float* k2  = (const float*)d_in[4];
    const float* rk2 = (const float*)d_in[5];
    const float* b2  = (const float*)d_in[6];
    const float* wd  = (const float*)d_in[7];
    const float* bd  = (const float*)d_in[8];
    float* out = (float*)d_out;

    dim3 grid(256), block(1024);
    hipLaunchKernelGGL(gru_stack_kernel, grid, block, 0, stream,
                       x, k1, rk1, b1, k2, rk2, b2, wd, bd, out);
}

// Round 15
// 1954.144 us; speedup vs baseline: 3.2042x; 1.2279x over previous
//
#include <hip/hip_runtime.h>
#include <math.h>

#define TT 1024
#define U1 128
#define U2 32

typedef float f2 __attribute__((ext_vector_type(2)));
typedef float f4 __attribute__((ext_vector_type(4)));

// v_pk_fma_f32, bit-exact-verified in R7/R10/R12:
// PK_LO: both halves of acc += w.{x,y} * h.x ; PK_HI: ... * h.y
#define PK_LO(acc, w, h) asm("v_pk_fma_f32 %0, %1, %2, %0 op_sel:[0,0,0] op_sel_hi:[1,0,1]" \
                             : "+v"(acc) : "v"(w), "v"(h))
#define PK_HI(acc, w, h) asm("v_pk_fma_f32 %0, %1, %2, %0 op_sel:[0,1,0] op_sel_hi:[1,1,1]" \
                             : "+v"(acc) : "v"(w), "v"(h))

__device__ __forceinline__ float fast_tanh(float v) {
    float e = __expf(2.f * v);      // NaN-free saturation
    return 1.f - 2.f / (e + 1.f);
}
__device__ __forceinline__ float fast_sig(float v) {
    return 1.f / (1.f + __expf(-v));
}

// SINGLE-BARRIER FUSED STEP. 256 blocks x 1024 threads; batches {2b,2b+1}.
// Octet per GRU1 unit U=t>>3; ol=t&7: pr=ol>>2 (col-pair role AND batch to
// update), uq=ol&3 (u-quarter [32uq,32uq+32)).
//   pr0 cols {z,r}=(U,128+U); pr1 cols {h, k2|rk2|0}=(256+U, ...).
// Dot: 8 f4 LDS reads/batch (padded h1p rows -> banks {0,4,8,12}), 32 pk
// per batch via PK_LO/HI. Quad-reduce (xor1,xor2) -> full 128-u sums; xor4
// swaps pr-halves; each lane batch-selects (sel=pr) and updates h1[U] of ITS
// batch in-register (replicated; ol==0/4 write h1+k2g to parity LDS).
// Waves 12-15 (U>=96): c1 weight slot is free -> overlaid with rk2 col
// 32*uq+(U-96) (u=j index); mini-dot vs packed h2b {A,B} via PK_HI weight-
// broadcast; in-wave gather (qb+0,1,2); GRU2 update lagged: phase p handles
// step p-2 with k2g[rpar]=k2*h1(p-2), h2b[rpar]=h2(p-3). Chain verified.
// ONE barrier/phase; all cross-phase buffers parity ping-pong.
__global__ __launch_bounds__(1024)
void gru_stack_kernel(const float* __restrict__ x,   // [512,1024,1]
                      const float* __restrict__ k1,  // [1,384]
                      const float* __restrict__ rk1, // [128,384]
                      const float* __restrict__ b1,  // [2,384]
                      const float* __restrict__ k2,  // [128,96]
                      const float* __restrict__ rk2, // [32,96]
                      const float* __restrict__ b2,  // [2,96]
                      const float* __restrict__ wd,  // [32,1]
                      const float* __restrict__ bd,  // [1]
                      float* __restrict__ out)       // [512,1]
{
    __shared__ __align__(16) float h1p[2][2][4][36]; // [par][batch][uq][32+pad]
    __shared__ __align__(16) f2    h2b[2][U2];       // [par][u2] = {h2A, h2B}
    __shared__ __align__(16) float k2g[2][2][96];    // [par][batch][col]
    __shared__ __align__(16) f2    xs2[TT];          // {xA, xB} per step

    const int t    = threadIdx.x;
    const int b0   = blockIdx.x * 2;
    const int oct  = t >> 3, ol = t & 7;
    const int pr   = ol >> 2;            // col-pair role == batch this lane updates
    const int uq   = ol & 3, ub = 32 * uq;
    const int U    = oct;
    const int lane = t & 63, qb = lane & ~3;
    const int r2   = U - 96;             // GRU2 unit (valid on waves 12-15)

    // ---- zero init + x staging ----
    if (t < 576) ((float*)h1p)[t] = 0.f;
    if (t < 64)  ((f2*)h2b)[t] = (f2){0.f, 0.f};
    if (t < 384) ((float*)k2g)[t] = 0.f;
    if (t < TT)  xs2[t] = (f2){ x[b0 * TT + t], x[(b0 + 1) * TT + t] };

    // ---- weights (64 floats/thread, honest VGPR regime) ----
    f2 w2[32];
#pragma unroll
    for (int j = 0; j < 32; ++j) {
        const int u = ub + j;
        if (pr == 0) {
            w2[j] = (f2){ rk1[u * 384 + U], rk1[u * 384 + 128 + U] };
        } else {
            float c1w;
            if (U < 96)       c1w = k2[u * 96 + U];
            else if (uq < 3)  c1w = rk2[j * 96 + 32 * uq + r2]; // mini: u = j
            else              c1w = 0.f;
            w2[j] = (f2){ rk1[u * 384 + 256 + U], c1w };
        }
    }

    // ---- GRU1 constants (all 8 lanes of octet U) + state for batch 'pr' ----
    const float k1z = k1[U], k1r = k1[128 + U], k1h = k1[256 + U];
    const float bz  = b1[U]       + b1[384 + U];
    const float br  = b1[128 + U] + b1[384 + 128 + U];
    const float bhx = b1[256 + U];
    const float bhr = b1[384 + 256 + U];
    float h_old = 0.f;
    // ---- GRU2 constants/state (waves 12-15, pr==1 lanes) ----
    float bz2 = 0, br2 = 0, bh2x = 0, bh2r = 0, h2A = 0.f, h2B = 0.f;
    if (U >= 96 && pr == 1) {
        bz2  = b2[r2]      + b2[96 + r2];
        br2  = b2[32 + r2] + b2[96 + 32 + r2];
        bh2x = b2[64 + r2];
        bh2r = b2[96 + 64 + r2];
    }

    __syncthreads();  // init visible

    for (int p = 0; p <= TT + 1; ++p) {
        const int wpar = p & 1, rpar = wpar ^ 1;

        if (p <= TT) {
            // ---- main dot: both batches, cols {c0,c1}, u in [ub,ub+32) ----
            const f4* pbA = (const f4*)&h1p[rpar][0][uq][0];
            const f4* pbB = (const f4*)&h1p[rpar][1][uq][0];
            f2 accA = {0.f, 0.f}, accB = {0.f, 0.f};
#pragma unroll
            for (int k = 0; k < 8; ++k) {
                const f4 a4 = pbA[k];
                const f4 b4 = pbB[k];
                const f2 alo = a4.lo, ahi = a4.hi;
                const f2 blo = b4.lo, bhi = b4.hi;
                PK_LO(accA, w2[4 * k],     alo);   // u = 4k
                PK_HI(accA, w2[4 * k + 1], alo);   // u = 4k+1
                PK_LO(accA, w2[4 * k + 2], ahi);   // u = 4k+2
                PK_HI(accA, w2[4 * k + 3], ahi);   // u = 4k+3
                PK_LO(accB, w2[4 * k],     blo);
                PK_HI(accB, w2[4 * k + 1], blo);
                PK_LO(accB, w2[4 * k + 2], bhi);
                PK_HI(accB, w2[4 * k + 3], bhi);
            }
            // ---- quad reduce (uq tree) -> full 128-u column sums ----
            f2 tA, tB;
            tA.x = __shfl_xor(accA.x, 1, 64); tA.y = __shfl_xor(accA.y, 1, 64);
            tB.x = __shfl_xor(accB.x, 1, 64); tB.y = __shfl_xor(accB.y, 1, 64);
            accA += tA; accB += tB;
            tA.x = __shfl_xor(accA.x, 2, 64); tA.y = __shfl_xor(accA.y, 2, 64);
            tB.x = __shfl_xor(accB.x, 2, 64); tB.y = __shfl_xor(accB.y, 2, 64);
            accA += tA; accB += tB;
            // ---- partner swap (pr halves exchange col-pairs) ----
            f2 othA, othB;
            othA.x = __shfl_xor(accA.x, 4, 64); othA.y = __shfl_xor(accA.y, 4, 64);
            othB.x = __shfl_xor(accB.x, 4, 64); othB.y = __shfl_xor(accB.y, 4, 64);
            // ---- batch-select: this lane finishes batch sel=pr ----
            const float zv = pr ? othB.x : accA.x;
            const float rv = pr ? othB.y : accA.y;
            const float hv = pr ? accB.x : othA.x;
            const float kv = pr ? accB.y : othA.y;   // k2 col sum (valid U<96)

            if (p < TT) {
                const f2 xp = xs2[p];
                const float xv = pr ? xp.y : xp.x;
                // GRU1: z/r = relu, hh = tanh (reset_after) - replicated
                const float z  = fmaxf(fmaf(xv, k1z, bz) + zv, 0.f);
                const float r  = fmaxf(fmaf(xv, k1r, br) + rv, 0.f);
                const float hh = fast_tanh(fmaf(xv, k1h, bhx) + r * (hv + bhr));
                h_old = fmaf(z, h_old - hh, hh);
                if ((ol & 3) == 0)                    // ol==0 (A), ol==4 (B)
                    h1p[wpar][pr][U >> 5][U & 31] = h_old;
            }
            if ((ol & 3) == 0 && U < 96)
                k2g[wpar][pr][U] = kv;                // k2 . h1(p-1)
        }

        if (t >= 768) {  // wave-uniform heavy block: waves 12-15
            // ---- mini dot: rk2 col (w2[].y overlay) vs packed h2 {A,B} ----
            const f4* ph2 = (const f4*)&h2b[rpar][0];
            f2 mAB = {0.f, 0.f};                      // {sumA, sumB}
#pragma unroll
            for (int k = 0; k < 16; ++k) {
                const f4 q = ph2[k];                  // {A[2k],B[2k],A[2k+1],B[2k+1]}
                const f2 qlo = q.lo, qhi = q.hi;
                PK_HI(mAB, qlo, w2[2 * k]);           // += {A,B}[2k]   * w.y
                PK_HI(mAB, qhi, w2[2 * k + 1]);       // += {A,B}[2k+1] * w.y
            }
            // ---- gather the 3 gate minis of this octet's pr1 quad ----
            f2 g0, g1, g2;
            g0.x = __shfl(mAB.x, qb + 0, 64); g0.y = __shfl(mAB.y, qb + 0, 64);
            g1.x = __shfl(mAB.x, qb + 1, 64); g1.y = __shfl(mAB.y, qb + 1, 64);
            g2.x = __shfl(mAB.x, qb + 2, 64); g2.y = __shfl(mAB.y, qb + 2, 64);
            if (p >= 2 && pr == 1) {
                // GRU2 step p-2: z/r = sigmoid, hh = relu (replicated on quad)
                {   // batch A
                    const float xz = k2g[rpar][0][r2];
                    const float xr = k2g[rpar][0][32 + r2];
                    const float xh = k2g[rpar][0][64 + r2];
                    const float z  = fast_sig(xz + g0.x + bz2);
                    const float rr = fast_sig(xr + g1.x + br2);
                    const float hh = fmaxf(xh + bh2x + rr * (g2.x + bh2r), 0.f);
                    h2A = fmaf(z, h2A - hh, hh);
                }
                {   // batch B
                    const float xz = k2g[rpar][1][r2];
                    const float xr = k2g[rpar][1][32 + r2];
                    const float xh = k2g[rpar][1][64 + r2];
                    const float z  = fast_sig(xz + g0.y + bz2);
                    const float rr = fast_sig(xr + g1.y + br2);
                    const float hh = fmaxf(xh + bh2x + rr * (g2.y + bh2r), 0.f);
                    h2B = fmaf(z, h2B - hh, hh);
                }
                if (uq == 0) h2b[wpar][r2] = (f2){h2A, h2B};
            }
        }
        __syncthreads();  // the ONLY barrier per phase
    }

    // ---- dense head: final h2 = h2(TT-1) in parity (TT+1)&1 == 1 ----
    if (t < 32) {
        const f2 hf = h2b[1][t];
        f2 pv = hf * wd[t];
#pragma unroll
        for (int m = 16; m >= 1; m >>= 1) {
            pv.x += __shfl_xor(pv.x, m, 64);
            pv.y += __shfl_xor(pv.y, m, 64);
        }
        if (t == 0) {
            out[b0]     = pv.x + bd[0];
            out[b0 + 1] = pv.y + bd[0];
        }
    }
}

extern "C" void kernel_launch(void* const* d_in, const int* in_sizes, int n_in,
                              void* d_out, int out_size, void* d_ws, size_t ws_size,
                              hipStream_t stream) {
    const float* x   = (const float*)d_in[0];
    const float* k1  = (const float*)d_in[1];
    const float* rk1 = (const float*)d_in[2];
    const float* b1  = (const float*)d_in[3];
    const float* k2  = (const float*)d_in[4];
    const float* rk2 = (const float*)d_in[5];
    const float* b2  = (const float*)d_in[6];
    const float* wd  = (const float*)d_in[7];
    const float* bd  = (const float*)d_in[8];
    float* out = (float*)d_out;

    dim3 grid(256), block(1024);
    hipLaunchKernelGGL(gru_stack_kernel, grid, block, 0, stream,
                       x, k1, rk1, b1, k2, rk2, b2, wd, bd, out);
}